// Round 2
// baseline (3000.083 us; speedup 1.0000x reference)
//
#include <hip/hip_runtime.h>
#include <cstdint>
#include <cmath>

#define Bsz  1024
#define Pdim 1024
#define Hdim 4096
#define Ndim 32
#define Ddim 512
#define Ktop 128

// ---------------------------------------------------------------------------
// Kernel 1: proximal GEMM  out[b,h] = dot(pin[b,:], W[h,:]) + bias[h]
// Scalar-broadcast structure: pin via s_load (uniform), W rows streamed into
// VGPRs. Thread owns 2 h-rows x 8 b's. Block = 512 h x 8 b.
// Grid: 8 htiles x 128 btiles = 1024 blocks; htile pinned per XCD (W panel
// 512 rows x 4KB = 2MB fits XCD L2).
// ---------------------------------------------------------------------------
__global__ __launch_bounds__(256, 4) void proximal_gemm(
    const float* __restrict__ pin, const float* __restrict__ W,
    const float* __restrict__ bias, float* __restrict__ out)
{
  const int t = threadIdx.x;
  const int ell = blockIdx.x;
  const int htile = ell & 7;        // one htile per XCD
  const int btile = ell >> 3;       // [0,128)
  const int h0 = htile * 512, b0 = btile * 8;

  float acc[2][8];
#pragma unroll
  for (int s = 0; s < 2; s++)
#pragma unroll
    for (int b = 0; b < 8; b++) acc[s][b] = 0.f;

  const float* wr = W + (size_t)(h0 + t) * Pdim;

  for (int d0 = 0; d0 < Pdim; d0 += 4) {
    float4 wv[2];
#pragma unroll
    for (int s = 0; s < 2; s++)
      wv[s] = *(const float4*)(wr + (size_t)s * 256 * Pdim + d0);
    const float* ar = pin + (size_t)b0 * Pdim + d0;   // uniform -> s_load
#pragma unroll
    for (int b = 0; b < 8; b++) {
      const float a0 = ar[b * Pdim + 0];
      const float a1 = ar[b * Pdim + 1];
      const float a2 = ar[b * Pdim + 2];
      const float a3 = ar[b * Pdim + 3];
#pragma unroll
      for (int s = 0; s < 2; s++)
        acc[s][b] += a0 * wv[s].x + a1 * wv[s].y + a2 * wv[s].z + a3 * wv[s].w;
    }
  }

#pragma unroll
  for (int s = 0; s < 2; s++) {
    const int h = h0 + s * 256 + t;
    const float bb = bias[h];
#pragma unroll
    for (int b = 0; b < 8; b++)
      out[(size_t)(b0 + b) * Hdim + h] = acc[s][b] + bb;  // lanes -> consec h
  }
}

// ---------------------------------------------------------------------------
// Kernel 2: distal GEMM + abs-argmax over n + sigmoid gate (RMW on out).
// din (A) via scalar path (wave-uniform s_load); distal (B) rows streamed
// per-thread from global (L1 line reuse over 8 iters). No LDS in main loop.
// Thread owns 4 n'-rows (n' = n0 + s*256 + t) x 32 b's -> acc[4][32].
// Block covers 1024 n' = 32 h, 32 b. Grid: 128 ntiles x 32 btiles = 4096.
// ---------------------------------------------------------------------------
__global__ __launch_bounds__(256, 2) void distal_gate(
    const float* __restrict__ din, const float* __restrict__ distal,
    float* __restrict__ out)
{
  __shared__ float xpose[256 * 33];   // epilogue transpose, padded stride 33
  const int t = threadIdx.x;

  const int ell = blockIdx.x;
  const int xcd = ell & 7;
  const int q   = ell >> 3;            // [0,512)
  const int ntile = xcd * 16 + (q >> 5);  // [0,128), panel pinned per XCD
  const int btile = q & 31;
  const int n0 = ntile * 1024, b0 = btile * 32;

  float acc[4][32];
#pragma unroll
  for (int s = 0; s < 4; s++)
#pragma unroll
    for (int b = 0; b < 32; b++) acc[s][b] = 0.f;

  const float* brow = distal + (size_t)(n0 + t) * Ddim;

  for (int d0 = 0; d0 < Ddim; d0 += 4) {
    float4 bv[4];
#pragma unroll
    for (int s = 0; s < 4; s++)
      bv[s] = *(const float4*)(brow + (size_t)s * 256 * Ddim + d0);
    const float* ar = din + (size_t)b0 * Ddim + d0;   // uniform -> s_load
#pragma unroll
    for (int b = 0; b < 32; b++) {
      const float a0 = ar[b * Ddim + 0];
      const float a1 = ar[b * Ddim + 1];
      const float a2 = ar[b * Ddim + 2];
      const float a3 = ar[b * Ddim + 3];
#pragma unroll
      for (int s = 0; s < 4; s++)
        acc[s][b] += a0 * bv[s].x + a1 * bv[s].y + a2 * bv[s].z + a3 * bv[s].w;
    }
  }

  // Epilogue: for each s-pass, transpose 256x32 through LDS, then each
  // thread scans one (h,b) column over n=0..31 (first-index argmax ties,
  // matching np.argmax), applies sigmoid gate to out.
  const int g = t >> 5;    // h sub-index within pass
  const int j = t & 31;    // b sub-index
  for (int s = 0; s < 4; s++) {
    __syncthreads();
#pragma unroll
    for (int b = 0; b < 32; b++) xpose[t * 33 + b] = acc[s][b];
    __syncthreads();
    float best   = xpose[(g * 32 + 0) * 33 + j];
    float bestab = fabsf(best);
#pragma unroll
    for (int n = 1; n < 32; n++) {
      const float v  = xpose[(g * 32 + n) * 33 + j];
      const float av = fabsf(v);
      if (av > bestab) { bestab = av; best = v; }
    }
    const float gate = 1.f / (1.f + expf(-best));
    const int h = ntile * 32 + s * 8 + g;
    out[(size_t)(b0 + j) * Hdim + h] *= gate;
  }
}

// ---------------------------------------------------------------------------
// Kernel 3: per-row top-k mask (in place). 256-bin MSB radix select,
// deterministic index-ordered tie inclusion. (unchanged from R1)
// ---------------------------------------------------------------------------
__device__ __forceinline__ unsigned keyf(float f) {
  unsigned u = __float_as_uint(f);
  return (u & 0x80000000u) ? ~u : (u | 0x80000000u);
}

__global__ __launch_bounds__(256) void topk_mask(float* __restrict__ out)
{
  __shared__ float vals[Hdim];
  __shared__ unsigned hist[256];
  __shared__ unsigned sc[4];
  __shared__ unsigned s_prefix, s_kk;
  const int t = threadIdx.x;
  float* row = out + (size_t)blockIdx.x * Hdim;

#pragma unroll
  for (int qq = 0; qq < 4; qq++) {
    float4 v = *(const float4*)(row + qq * 1024 + t * 4);
    *(float4*)&vals[qq * 1024 + t * 4] = v;
  }
  if (t == 0) { s_prefix = 0u; s_kk = Ktop; }
  __syncthreads();

  for (int shift = 24; shift >= 0; shift -= 8) {
    hist[t] = 0u;
    __syncthreads();
    const unsigned prefix = s_prefix;
    const unsigned maskhi = (shift == 24) ? 0u : (0xFFFFFFFFu << (shift + 8));
    for (int c = 0; c < 16; c++) {
      unsigned u = keyf(vals[c * 256 + t]);
      if ((u & maskhi) == prefix)
        atomicAdd(&hist[(u >> shift) & 255u], 1u);
    }
    __syncthreads();
    if (t == 0) {
      unsigned kk = s_kk, cum = 0;
      int bin = 255;
      for (; bin > 0; --bin) {
        unsigned c = hist[bin];
        if (cum + c >= kk) break;
        cum += c;
      }
      s_kk = kk - cum;
      s_prefix = prefix | ((unsigned)bin << shift);
    }
    __syncthreads();
  }
  const unsigned T  = s_prefix;
  const unsigned kk = s_kk;

  const int lane = t & 63, w = t >> 6;
  unsigned running = 0;
  for (int c = 0; c < 16; c++) {
    const int h = c * 256 + t;
    const float v = vals[h];
    const unsigned u = keyf(v);
    const bool tie = (u == T);
    unsigned long long m = __ballot(tie);
    unsigned lpfx = (unsigned)__popcll(m & ((1ull << lane) - 1ull));
    if (lane == 0) sc[w] = (unsigned)__popcll(m);
    __syncthreads();
    unsigned off = 0;
#pragma unroll
    for (int ww = 0; ww < 4; ww++) if (ww < w) off += sc[ww];
    const unsigned rank = running + off + lpfx;
    row[h] = (u > T) ? v : ((tie && rank < kk) ? v : 0.f);
    const unsigned tot = sc[0] + sc[1] + sc[2] + sc[3];
    __syncthreads();
    running += tot;
  }
}

extern "C" void kernel_launch(void* const* d_in, const int* in_sizes, int n_in,
                              void* d_out, int out_size, void* d_ws, size_t ws_size,
                              hipStream_t stream)
{
  (void)in_sizes; (void)n_in; (void)d_ws; (void)ws_size; (void)out_size;
  const float* pin  = (const float*)d_in[0];  // (B,P)
  const float* dinp = (const float*)d_in[1];  // (B,D)
  const float* W    = (const float*)d_in[2];  // (H,P)
  const float* bias = (const float*)d_in[3];  // (H,)
  const float* dst  = (const float*)d_in[4];  // (H,N,D)
  float* out = (float*)d_out;                 // (B,H)

  hipLaunchKernelGGL(proximal_gemm, dim3(1024), dim3(256), 0, stream, pin, W, bias, out);
  hipLaunchKernelGGL(distal_gate,   dim3(4096), dim3(256), 0, stream, dinp, dst, out);
  hipLaunchKernelGGL(topk_mask,     dim3(Bsz),  dim3(256), 0, stream, out);
}

// Round 4
// 717.874 us; speedup vs baseline: 4.1791x; 4.1791x over previous
//
#include <hip/hip_runtime.h>
#include <cstdint>
#include <cmath>

#define Bsz  1024
#define Pdim 1024
#define Hdim 4096
#define Ndim 32
#define Ddim 512
#define Ktop 128

typedef _Float16 f16x8 __attribute__((ext_vector_type(8)));
typedef float    f32x4 __attribute__((ext_vector_type(4)));

#define GLDS(gsrc, ldst)                                                        \
  __builtin_amdgcn_global_load_lds(                                             \
      (const __attribute__((address_space(1))) unsigned int*)(gsrc),            \
      (__attribute__((address_space(3))) unsigned int*)(ldst), 16, 0, 0)

// ws layout: distal images at byte 0 (256 MB), din images at byte 268435456 (2 MB).
// Image for (tile, kstep) = 16 KB: [0,8K) hi, [8K,16K) lo*256. Element (r,k):
// byte = r*64 + (((k>>3)*16) ^ ((r&3)<<4)) + (k&7)*2
// Swizzle uses ONLY bits 4-5 (row is 64 B = 4 chunks) -> bijective per row.
#define WS_NEEDED 270532608ull

// ---------------------------------------------------------------------------
// Kernel 1: proximal GEMM (fp32, unchanged from R1 — passed, low risk)
// ---------------------------------------------------------------------------
__global__ __launch_bounds__(256) void proximal_gemm(
    const float* __restrict__ pin, const float* __restrict__ W,
    const float* __restrict__ bias, float* __restrict__ out)
{
  __shared__ float Blds[32 * 256];
  __shared__ float Alds[32 * 32];
  const int t  = threadIdx.x;
  const int l  = t & 63;
  const int wv = t >> 6;

  const int ell   = blockIdx.x;
  const int xcd   = ell & 7;
  const int q     = ell >> 3;
  const int htile = xcd * 2 + (q >> 5);
  const int btile = q & 31;
  const int h0 = htile * 256, b0 = btile * 32;

  float acc[8][4];
#pragma unroll
  for (int i = 0; i < 8; i++)
    for (int j = 0; j < 4; j++) acc[i][j] = 0.f;

  const float* wrow = W + (size_t)(h0 + t) * Pdim;
  const int ab = t >> 3, ak = (t & 7) * 4;
  const float* arow = pin + (size_t)(b0 + ab) * Pdim + ak;

  for (int kt = 0; kt < Pdim / 32; ++kt) {
    const int p0 = kt * 32;
    float wbuf[32];
#pragma unroll
    for (int f = 0; f < 8; f++) {
      float4 v = *(const float4*)(wrow + p0 + f * 4);
      wbuf[f * 4 + 0] = v.x; wbuf[f * 4 + 1] = v.y;
      wbuf[f * 4 + 2] = v.z; wbuf[f * 4 + 3] = v.w;
    }
    float4 av = *(const float4*)(arow + p0);
    __syncthreads();
#pragma unroll
    for (int f = 0; f < 32; f++) Blds[f * 256 + t] = wbuf[f];
    Alds[(ak + 0) * 32 + ab] = av.x;
    Alds[(ak + 1) * 32 + ab] = av.y;
    Alds[(ak + 2) * 32 + ab] = av.z;
    Alds[(ak + 3) * 32 + ab] = av.w;
    __syncthreads();
#pragma unroll
    for (int k = 0; k < 32; k++) {
      float4 bv  = *(const float4*)&Blds[k * 256 + 4 * l];
      float4 alo = *(const float4*)&Alds[k * 32 + 8 * wv];
      float4 ahi = *(const float4*)&Alds[k * 32 + 8 * wv + 4];
      float a0[8] = {alo.x, alo.y, alo.z, alo.w, ahi.x, ahi.y, ahi.z, ahi.w};
#pragma unroll
      for (int i = 0; i < 8; i++) {
        acc[i][0] += a0[i] * bv.x;
        acc[i][1] += a0[i] * bv.y;
        acc[i][2] += a0[i] * bv.z;
        acc[i][3] += a0[i] * bv.w;
      }
    }
  }
  float4 bb = *(const float4*)(bias + h0 + 4 * l);
#pragma unroll
  for (int i = 0; i < 8; i++) {
    float4 o;
    o.x = acc[i][0] + bb.x;
    o.y = acc[i][1] + bb.y;
    o.z = acc[i][2] + bb.z;
    o.w = acc[i][3] + bb.w;
    *(float4*)(out + (size_t)(b0 + 8 * wv + i) * Hdim + h0 + 4 * l) = o;
  }
}

// ---------------------------------------------------------------------------
// Convert kernels: fp32 -> (hi fp16, lo*256 fp16) tile images in ws.
// One thread = one 16B chunk (8 elems): reads 32B contiguous, writes 2x16B.
// ---------------------------------------------------------------------------
__global__ __launch_bounds__(256) void convert_distal(
    const float* __restrict__ src, char* __restrict__ dstA)
{
  const int gid = blockIdx.x * 256 + threadIdx.x;  // 131072 rows * 64 chunks
  const int np_ = gid >> 6;
  const int e   = (gid & 63) * 8;
  float4 v0 = *(const float4*)(src + (size_t)np_ * Ddim + e);
  float4 v1 = *(const float4*)(src + (size_t)np_ * Ddim + e + 4);
  const int ntile = np_ >> 7, r = np_ & 127, ks = e >> 5, k = e & 31;
  char* base = dstA + (size_t)(ntile * 16 + ks) * 16384;
  const int off = r * 64 + (((k >> 3) * 16) ^ ((r & 3) << 4));
  const float f[8] = {v0.x, v0.y, v0.z, v0.w, v1.x, v1.y, v1.z, v1.w};
  f16x8 hi, lo;
#pragma unroll
  for (int j = 0; j < 8; j++) {
    const _Float16 h = (_Float16)f[j];
    hi[j] = h;
    lo[j] = (_Float16)((f[j] - (float)h) * 256.f);
  }
  *(f16x8*)(base + off)        = hi;
  *(f16x8*)(base + 8192 + off) = lo;
}

__global__ __launch_bounds__(256) void convert_din(
    const float* __restrict__ src, char* __restrict__ dstB)
{
  const int gid = blockIdx.x * 256 + threadIdx.x;  // 1024 rows * 64 chunks
  const int b   = gid >> 6;
  const int e   = (gid & 63) * 8;
  float4 v0 = *(const float4*)(src + (size_t)b * Ddim + e);
  float4 v1 = *(const float4*)(src + (size_t)b * Ddim + e + 4);
  const int btile = b >> 7, c = b & 127, ks = e >> 5, k = e & 31;
  char* base = dstB + (size_t)(btile * 16 + ks) * 16384;
  const int off = c * 64 + (((k >> 3) * 16) ^ ((c & 3) << 4));
  const float f[8] = {v0.x, v0.y, v0.z, v0.w, v1.x, v1.y, v1.z, v1.w};
  f16x8 hi, lo;
#pragma unroll
  for (int j = 0; j < 8; j++) {
    const _Float16 h = (_Float16)f[j];
    hi[j] = h;
    lo[j] = (_Float16)((f[j] - (float)h) * 256.f);
  }
  *(f16x8*)(base + off)        = hi;
  *(f16x8*)(base + 8192 + off) = lo;
}

// ---------------------------------------------------------------------------
// Kernel 2: distal GEMM via fp16 3-term split MFMA + abs-argmax + gate RMW.
// C tile 128 (n') x 128 (b); 4 waves in 2x2; acc 4x4 frags of 16x16;
// K = 512 in 16 steps of 32. acc_hh scale 1, acc_x scale 256 (lo pre-scaled).
// ---------------------------------------------------------------------------
__global__ __launch_bounds__(256, 2) void distal_mfma(
    const char* __restrict__ Aw, const char* __restrict__ Bw,
    float* __restrict__ out)
{
  __shared__ _Float16 lds[16384];  // 32KB: Ahi|Alo|Bhi|Blo (8KB each)
  const int t = threadIdx.x, lane = t & 63, wv = t >> 6;
  const int g = lane >> 4, c15 = lane & 15;
  const int wrow0 = (wv >> 1) * 64, wcol0 = (wv & 1) * 64;

  const int blk = blockIdx.x;
  const int xcd = blk & 7, q = blk >> 3;
  const int ntile = xcd * 128 + (q >> 3);   // [0,1024)
  const int btile = q & 7;                  // [0,8)

  f32x4 acc[4][4], accx[4][4];
#pragma unroll
  for (int mi = 0; mi < 4; mi++)
#pragma unroll
    for (int ni = 0; ni < 4; ni++) {
      acc[mi][ni]  = (f32x4){0.f, 0.f, 0.f, 0.f};
      accx[mi][ni] = (f32x4){0.f, 0.f, 0.f, 0.f};
    }

  const char* Abase = Aw + (size_t)(ntile * 16) * 16384;
  const char* Bbase = Bw + (size_t)(btile * 16) * 16384;

  for (int ks = 0; ks < 16; ++ks) {
    const char* As = Abase + ks * 16384;
    const char* Bs = Bbase + ks * 16384;
#pragma unroll
    for (int j = 0; j < 4; j++) {
      const int ch = j * 4 + wv;
      GLDS(As + ch * 1024 + lane * 16, (char*)lds + ch * 1024);
      GLDS(Bs + ch * 1024 + lane * 16, (char*)lds + 16384 + ch * 1024);
    }
    __syncthreads();   // drains vmcnt -> staged data visible

    f16x8 ah[4], al[4], bh[4], bl[4];
#pragma unroll
    for (int mi = 0; mi < 4; mi++) {
      const int r   = wrow0 + mi * 16 + c15;
      const int off = r * 64 + ((g * 16) ^ ((r & 3) << 4));
      ah[mi] = *(const f16x8*)((const char*)lds + off);
      al[mi] = *(const f16x8*)((const char*)lds + 8192 + off);
    }
#pragma unroll
    for (int ni = 0; ni < 4; ni++) {
      const int c   = wcol0 + ni * 16 + c15;
      const int off = c * 64 + ((g * 16) ^ ((c & 3) << 4));
      bh[ni] = *(const f16x8*)((const char*)lds + 16384 + off);
      bl[ni] = *(const f16x8*)((const char*)lds + 24576 + off);
    }
#pragma unroll
    for (int mi = 0; mi < 4; mi++)
#pragma unroll
      for (int ni = 0; ni < 4; ni++) {
        acc[mi][ni]  = __builtin_amdgcn_mfma_f32_16x16x32_f16(ah[mi], bh[ni], acc[mi][ni],  0, 0, 0);
        accx[mi][ni] = __builtin_amdgcn_mfma_f32_16x16x32_f16(ah[mi], bl[ni], accx[mi][ni], 0, 0, 0);
        accx[mi][ni] = __builtin_amdgcn_mfma_f32_16x16x32_f16(al[mi], bh[ni], accx[mi][ni], 0, 0, 0);
      }
    __syncthreads();   // safe to overwrite LDS next step
  }

  // Epilogue: per (h,b) abs-argmax over n=32 rows, first-index ties (numpy),
  // then gate RMW on out. C/D frag: col=lane&15 (b), row=(lane>>4)*4+reg (n').
#pragma unroll
  for (int hh = 0; hh < 2; ++hh) {
#pragma unroll
    for (int ni = 0; ni < 4; ++ni) {
      float bestA = -1.f, bestV = 0.f;
      int   bestN = 999;
#pragma unroll
      for (int m2 = 0; m2 < 2; ++m2) {
        const int mi = hh * 2 + m2;
#pragma unroll
        for (int reg = 0; reg < 4; ++reg) {
          const float v = acc[mi][ni][reg] + accx[mi][ni][reg] * 0.00390625f;
          const float a = fabsf(v);
          const int   n = m2 * 16 + g * 4 + reg;   // ascending within thread
          if (a > bestA) { bestA = a; bestV = v; bestN = n; }
        }
      }
#pragma unroll
      for (int m = 16; m <= 32; m <<= 1) {
        const float oa = __shfl_xor(bestA, m, 64);
        const float ov = __shfl_xor(bestV, m, 64);
        const int   on = __shfl_xor(bestN, m, 64);
        if (oa > bestA || (oa == bestA && on < bestN)) {
          bestA = oa; bestV = ov; bestN = on;
        }
      }
      if (g == 0) {
        const int bcol = btile * 128 + wcol0 + ni * 16 + c15;
        const int h    = ntile * 4 + (wv >> 1) * 2 + hh;
        const float gate = 1.f / (1.f + expf(-bestV));
        out[(size_t)bcol * Hdim + h] *= gate;
      }
    }
  }
}

// ---------------------------------------------------------------------------
// Fallback distal kernel (R1, fp32 VALU) if ws is too small.
// ---------------------------------------------------------------------------
__global__ __launch_bounds__(256) void distal_gate_fb(
    const float* __restrict__ din, const float* __restrict__ distal,
    float* __restrict__ out)
{
  __shared__ float Blds[32 * 256];
  __shared__ float Alds[32 * 32];
  const int t  = threadIdx.x;
  const int l  = t & 63;
  const int wv = t >> 6;
  const int ell   = blockIdx.x;
  const int xcd   = ell & 7;
  const int q     = ell >> 3;
  const int htile = xcd * 64 + (q >> 5);
  const int btile = q & 31;
  const int n0 = htile * 256, b0 = btile * 32;

  float acc[8][4];
#pragma unroll
  for (int i = 0; i < 8; i++)
    for (int j = 0; j < 4; j++) acc[i][j] = 0.f;

  const float* brow = distal + (size_t)(n0 + t) * Ddim;
  const int ab = t >> 3, ak = (t & 7) * 4;
  const float* arow = din + (size_t)(b0 + ab) * Ddim + ak;

  for (int kt = 0; kt < Ddim / 32; ++kt) {
    const int d0 = kt * 32;
    float wbuf[32];
#pragma unroll
    for (int f = 0; f < 8; f++) {
      float4 v = *(const float4*)(brow + d0 + f * 4);
      wbuf[f * 4 + 0] = v.x; wbuf[f * 4 + 1] = v.y;
      wbuf[f * 4 + 2] = v.z; wbuf[f * 4 + 3] = v.w;
    }
    float4 av = *(const float4*)(arow + d0);
    __syncthreads();
#pragma unroll
    for (int f = 0; f < 32; f++) Blds[f * 256 + t] = wbuf[f];
    Alds[(ak + 0) * 32 + ab] = av.x;
    Alds[(ak + 1) * 32 + ab] = av.y;
    Alds[(ak + 2) * 32 + ab] = av.z;
    Alds[(ak + 3) * 32 + ab] = av.w;
    __syncthreads();
#pragma unroll
    for (int k = 0; k < 32; k++) {
      float4 bv  = *(const float4*)&Blds[k * 256 + 4 * l];
      float4 alo = *(const float4*)&Alds[k * 32 + 8 * wv];
      float4 ahi = *(const float4*)&Alds[k * 32 + 8 * wv + 4];
      float a0[8] = {alo.x, alo.y, alo.z, alo.w, ahi.x, ahi.y, ahi.z, ahi.w};
#pragma unroll
      for (int i = 0; i < 8; i++) {
        acc[i][0] += a0[i] * bv.x;
        acc[i][1] += a0[i] * bv.y;
        acc[i][2] += a0[i] * bv.z;
        acc[i][3] += a0[i] * bv.w;
      }
    }
  }
  const int i0  = l & 7;
  const int grp = l >> 3;
  float v = 0.f;
#pragma unroll
  for (int bi = 0; bi < 8; bi++) {
    float bav = fabsf(acc[bi][0]);
    float bv_ = acc[bi][0];
    int   bn  = 4 * i0;
#pragma unroll
    for (int j = 1; j < 4; j++) {
      float av2 = fabsf(acc[bi][j]);
      if (av2 > bav) { bav = av2; bv_ = acc[bi][j]; bn = 4 * i0 + j; }
    }
#pragma unroll
    for (int m = 1; m < 8; m <<= 1) {
      float oav = __shfl_xor(bav, m, 64);
      float ov  = __shfl_xor(bv_, m, 64);
      int   on  = __shfl_xor(bn,  m, 64);
      if (oav > bav || (oav == bav && on < bn)) { bav = oav; bv_ = ov; bn = on; }
    }
    if (bi == i0) v = bv_;
  }
  const float gate = 1.f / (1.f + expf(-v));
  const size_t idx = (size_t)(b0 + 8 * wv + i0) * Hdim + (size_t)htile * 8 + grp;
  out[idx] *= gate;
}

// ---------------------------------------------------------------------------
// Kernel 3: per-row top-k mask (unchanged).
// ---------------------------------------------------------------------------
__device__ __forceinline__ unsigned keyf(float f) {
  unsigned u = __float_as_uint(f);
  return (u & 0x80000000u) ? ~u : (u | 0x80000000u);
}

__global__ __launch_bounds__(256) void topk_mask(float* __restrict__ out)
{
  __shared__ float vals[Hdim];
  __shared__ unsigned hist[256];
  __shared__ unsigned sc[4];
  __shared__ unsigned s_prefix, s_kk;
  const int t = threadIdx.x;
  float* row = out + (size_t)blockIdx.x * Hdim;

#pragma unroll
  for (int qq = 0; qq < 4; qq++) {
    float4 v = *(const float4*)(row + qq * 1024 + t * 4);
    *(float4*)&vals[qq * 1024 + t * 4] = v;
  }
  if (t == 0) { s_prefix = 0u; s_kk = Ktop; }
  __syncthreads();

  for (int shift = 24; shift >= 0; shift -= 8) {
    hist[t] = 0u;
    __syncthreads();
    const unsigned prefix = s_prefix;
    const unsigned maskhi = (shift == 24) ? 0u : (0xFFFFFFFFu << (shift + 8));
    for (int c = 0; c < 16; c++) {
      unsigned u = keyf(vals[c * 256 + t]);
      if ((u & maskhi) == prefix)
        atomicAdd(&hist[(u >> shift) & 255u], 1u);
    }
    __syncthreads();
    if (t == 0) {
      unsigned kk = s_kk, cum = 0;
      int bin = 255;
      for (; bin > 0; --bin) {
        unsigned c = hist[bin];
        if (cum + c >= kk) break;
        cum += c;
      }
      s_kk = kk - cum;
      s_prefix = prefix | ((unsigned)bin << shift);
    }
    __syncthreads();
  }
  const unsigned T  = s_prefix;
  const unsigned kk = s_kk;

  const int lane = t & 63, w = t >> 6;
  unsigned running = 0;
  for (int c = 0; c < 16; c++) {
    const int h = c * 256 + t;
    const float v = vals[h];
    const unsigned u = keyf(v);
    const bool tie = (u == T);
    unsigned long long m = __ballot(tie);
    unsigned lpfx = (unsigned)__popcll(m & ((1ull << lane) - 1ull));
    if (lane == 0) sc[w] = (unsigned)__popcll(m);
    __syncthreads();
    unsigned off = 0;
#pragma unroll
    for (int ww = 0; ww < 4; ww++) if (ww < w) off += sc[ww];
    const unsigned rank = running + off + lpfx;
    row[h] = (u > T) ? v : ((tie && rank < kk) ? v : 0.f);
    const unsigned tot = sc[0] + sc[1] + sc[2] + sc[3];
    __syncthreads();
    running += tot;
  }
}

extern "C" void kernel_launch(void* const* d_in, const int* in_sizes, int n_in,
                              void* d_out, int out_size, void* d_ws, size_t ws_size,
                              hipStream_t stream)
{
  (void)in_sizes; (void)n_in; (void)out_size;
  const float* pin  = (const float*)d_in[0];  // (B,P)
  const float* dinp = (const float*)d_in[1];  // (B,D)
  const float* W    = (const float*)d_in[2];  // (H,P)
  const float* bias = (const float*)d_in[3];  // (H,)
  const float* dst  = (const float*)d_in[4];  // (H,N,D)
  float* out = (float*)d_out;                 // (B,H)

  hipLaunchKernelGGL(proximal_gemm, dim3(512), dim3(256), 0, stream, pin, W, bias, out);

  if (ws_size >= WS_NEEDED) {
    char* Aw = (char*)d_ws;                 // 256 MB distal images
    char* Bw = (char*)d_ws + 268435456ull;  // 2 MB din images
    hipLaunchKernelGGL(convert_distal, dim3(32768), dim3(256), 0, stream, dst,  Aw);
    hipLaunchKernelGGL(convert_din,    dim3(256),   dim3(256), 0, stream, dinp, Bw);
    hipLaunchKernelGGL(distal_mfma,    dim3(8192),  dim3(256), 0, stream, Aw, Bw, out);
  } else {
    hipLaunchKernelGGL(distal_gate_fb, dim3(16384), dim3(256), 0, stream, dinp, dst, out);
  }

  hipLaunchKernelGGL(topk_mask, dim3(Bsz), dim3(256), 0, stream, out);
}

// Round 5
// 699.287 us; speedup vs baseline: 4.2902x; 1.0266x over previous
//
#include <hip/hip_runtime.h>
#include <cstdint>
#include <cmath>

#define Bsz  1024
#define Pdim 1024
#define Hdim 4096
#define Ndim 32
#define Ddim 512
#define Ktop 128

typedef _Float16 f16x8 __attribute__((ext_vector_type(8)));
typedef float    f32x4 __attribute__((ext_vector_type(4)));

#define GLDS(gsrc, ldst)                                                        \
  __builtin_amdgcn_global_load_lds(                                             \
      (const __attribute__((address_space(1))) unsigned int*)(gsrc),            \
      (__attribute__((address_space(3))) unsigned int*)(ldst), 16, 0, 0)

// ws layout: distal images at byte 0 (256 MB), din images at byte 268435456 (2 MB).
// Image per (tile, kstep) = 16 KB, FRAGMENT-LINEAR:
//   [hi: frag f=0..7][lo: frag f=0..7], each frag 1024 B.
// Fragment f covers rows 16f..16f+15 (of the 128-row tile), k = 0..31.
// Element (r,k) -> frag (r>>4), byte within frag = ((k>>3)*16 + (r&15))*16 + (k&7)*2
// (lane l = (k>>3)*16 + (r&15) holds row r&15, k in [8*(l>>4), +8) -- the
// gfx950 16x16x32 A/B fragment order, HW-verified by R4's pass).
// ds_read is then wave-uniform base + lane*16 -> zero bank conflicts.
#define WS_NEEDED 270532608ull

// ---------------------------------------------------------------------------
// Kernel 1: proximal GEMM (fp32, unchanged from R1 — passed, low risk)
// ---------------------------------------------------------------------------
__global__ __launch_bounds__(256) void proximal_gemm(
    const float* __restrict__ pin, const float* __restrict__ W,
    const float* __restrict__ bias, float* __restrict__ out)
{
  __shared__ float Blds[32 * 256];
  __shared__ float Alds[32 * 32];
  const int t  = threadIdx.x;
  const int l  = t & 63;
  const int wv = t >> 6;

  const int ell   = blockIdx.x;
  const int xcd   = ell & 7;
  const int q     = ell >> 3;
  const int htile = xcd * 2 + (q >> 5);
  const int btile = q & 31;
  const int h0 = htile * 256, b0 = btile * 32;

  float acc[8][4];
#pragma unroll
  for (int i = 0; i < 8; i++)
    for (int j = 0; j < 4; j++) acc[i][j] = 0.f;

  const float* wrow = W + (size_t)(h0 + t) * Pdim;
  const int ab = t >> 3, ak = (t & 7) * 4;
  const float* arow = pin + (size_t)(b0 + ab) * Pdim + ak;

  for (int kt = 0; kt < Pdim / 32; ++kt) {
    const int p0 = kt * 32;
    float wbuf[32];
#pragma unroll
    for (int f = 0; f < 8; f++) {
      float4 v = *(const float4*)(wrow + p0 + f * 4);
      wbuf[f * 4 + 0] = v.x; wbuf[f * 4 + 1] = v.y;
      wbuf[f * 4 + 2] = v.z; wbuf[f * 4 + 3] = v.w;
    }
    float4 av = *(const float4*)(arow + p0);
    __syncthreads();
#pragma unroll
    for (int f = 0; f < 32; f++) Blds[f * 256 + t] = wbuf[f];
    Alds[(ak + 0) * 32 + ab] = av.x;
    Alds[(ak + 1) * 32 + ab] = av.y;
    Alds[(ak + 2) * 32 + ab] = av.z;
    Alds[(ak + 3) * 32 + ab] = av.w;
    __syncthreads();
#pragma unroll
    for (int k = 0; k < 32; k++) {
      float4 bv  = *(const float4*)&Blds[k * 256 + 4 * l];
      float4 alo = *(const float4*)&Alds[k * 32 + 8 * wv];
      float4 ahi = *(const float4*)&Alds[k * 32 + 8 * wv + 4];
      float a0[8] = {alo.x, alo.y, alo.z, alo.w, ahi.x, ahi.y, ahi.z, ahi.w};
#pragma unroll
      for (int i = 0; i < 8; i++) {
        acc[i][0] += a0[i] * bv.x;
        acc[i][1] += a0[i] * bv.y;
        acc[i][2] += a0[i] * bv.z;
        acc[i][3] += a0[i] * bv.w;
      }
    }
  }
  float4 bb = *(const float4*)(bias + h0 + 4 * l);
#pragma unroll
  for (int i = 0; i < 8; i++) {
    float4 o;
    o.x = acc[i][0] + bb.x;
    o.y = acc[i][1] + bb.y;
    o.z = acc[i][2] + bb.z;
    o.w = acc[i][3] + bb.w;
    *(float4*)(out + (size_t)(b0 + 8 * wv + i) * Hdim + h0 + 4 * l) = o;
  }
}

// ---------------------------------------------------------------------------
// Convert kernels: fp32 -> (hi fp16, lo*256 fp16) fragment-linear images.
// One thread = one 16B chunk (8 elems along k).
// ---------------------------------------------------------------------------
__global__ __launch_bounds__(256) void convert_distal(
    const float* __restrict__ src, char* __restrict__ dstA)
{
  const int gid = blockIdx.x * 256 + threadIdx.x;  // 131072 rows * 64 chunks
  const int np_ = gid >> 6;
  const int e   = (gid & 63) * 8;
  float4 v0 = *(const float4*)(src + (size_t)np_ * Ddim + e);
  float4 v1 = *(const float4*)(src + (size_t)np_ * Ddim + e + 4);
  const int ntile = np_ >> 7, r = np_ & 127, ks = e >> 5, k = e & 31;
  char* base = dstA + (size_t)(ntile * 16 + ks) * 16384;
  const int off = (r >> 4) * 1024 + (((k >> 3) * 16 + (r & 15)) * 16);
  const float f[8] = {v0.x, v0.y, v0.z, v0.w, v1.x, v1.y, v1.z, v1.w};
  f16x8 hi, lo;
#pragma unroll
  for (int j = 0; j < 8; j++) {
    const _Float16 h = (_Float16)f[j];
    hi[j] = h;
    lo[j] = (_Float16)((f[j] - (float)h) * 256.f);
  }
  *(f16x8*)(base + off)        = hi;
  *(f16x8*)(base + 8192 + off) = lo;
}

__global__ __launch_bounds__(256) void convert_din(
    const float* __restrict__ src, char* __restrict__ dstB)
{
  const int gid = blockIdx.x * 256 + threadIdx.x;  // 1024 rows * 64 chunks
  const int b   = gid >> 6;
  const int e   = (gid & 63) * 8;
  float4 v0 = *(const float4*)(src + (size_t)b * Ddim + e);
  float4 v1 = *(const float4*)(src + (size_t)b * Ddim + e + 4);
  const int btile = b >> 7, c = b & 127, ks = e >> 5, k = e & 31;
  char* base = dstB + (size_t)(btile * 16 + ks) * 16384;
  const int off = (c >> 4) * 1024 + (((k >> 3) * 16 + (c & 15)) * 16);
  const float f[8] = {v0.x, v0.y, v0.z, v0.w, v1.x, v1.y, v1.z, v1.w};
  f16x8 hi, lo;
#pragma unroll
  for (int j = 0; j < 8; j++) {
    const _Float16 h = (_Float16)f[j];
    hi[j] = h;
    lo[j] = (_Float16)((f[j] - (float)h) * 256.f);
  }
  *(f16x8*)(base + off)        = hi;
  *(f16x8*)(base + 8192 + off) = lo;
}

// ---------------------------------------------------------------------------
// Kernel 2: distal GEMM via fp16 3-term split MFMA, double-buffered LDS,
// fragment-linear layout (zero bank conflicts), 1 barrier per K-step with
// next-step GLDS in flight under the MFMAs. Epilogue: abs-argmax + gate RMW.
// ---------------------------------------------------------------------------
__global__ __launch_bounds__(256, 2) void distal_mfma(
    const char* __restrict__ Aw, const char* __restrict__ Bw,
    float* __restrict__ out)
{
  __shared__ __align__(16) char lds[2][32768];  // [Ahi|Alo|Bhi|Blo] x 8KB
  const int t = threadIdx.x, lane = t & 63, wv = t >> 6;
  const int g = lane >> 4, c15 = lane & 15;
  const int wrow0 = (wv >> 1) * 64, wcol0 = (wv & 1) * 64;

  const int blk = blockIdx.x;
  const int xcd = blk & 7, q = blk >> 3;
  const int ntile = xcd * 128 + (q >> 3);   // [0,1024)
  const int btile = q & 7;                  // [0,8)

  f32x4 acc[4][4], accx[4][4];
#pragma unroll
  for (int mi = 0; mi < 4; mi++)
#pragma unroll
    for (int ni = 0; ni < 4; ni++) {
      acc[mi][ni]  = (f32x4){0.f, 0.f, 0.f, 0.f};
      accx[mi][ni] = (f32x4){0.f, 0.f, 0.f, 0.f};
    }

  const char* Abase = Aw + (size_t)(ntile * 16) * 16384;
  const char* Bbase = Bw + (size_t)(btile * 16) * 16384;

  // Stage K-step ks into LDS buffer bufp (8 GLDS wave-instrs per wave,
  // 32 KB per block total; dest linear = lane*16, matches image layout).
  auto STAGE = [&](char* bufp, int ks) {
    const char* As = Abase + ks * 16384;
    const char* Bs = Bbase + ks * 16384;
#pragma unroll
    for (int j = 0; j < 4; j++) {
      const int ch = j * 4 + wv;   // 16 chunks of 1024B for A (hi+lo)
      GLDS(As + ch * 1024 + lane * 16, bufp + ch * 1024);
      GLDS(Bs + ch * 1024 + lane * 16, bufp + 16384 + ch * 1024);
    }
  };

  STAGE(lds[0], 0);
  __syncthreads();   // prologue drain

  int cur = 0;
  for (int ks = 0; ks < 16; ++ks) {
    if (ks < 15) STAGE(lds[cur ^ 1], ks + 1);   // in flight under MFMAs

    const char* L = lds[cur];
    f16x8 ah[4], al[4], bh[4], bl[4];
#pragma unroll
    for (int mi = 0; mi < 4; mi++) {
      const int f = (wv >> 1) * 4 + mi;
      ah[mi] = *(const f16x8*)(L + f * 1024 + lane * 16);
      al[mi] = *(const f16x8*)(L + 8192 + f * 1024 + lane * 16);
    }
#pragma unroll
    for (int ni = 0; ni < 4; ni++) {
      const int f = (wv & 1) * 4 + ni;
      bh[ni] = *(const f16x8*)(L + 16384 + f * 1024 + lane * 16);
      bl[ni] = *(const f16x8*)(L + 24576 + f * 1024 + lane * 16);
    }
#pragma unroll
    for (int mi = 0; mi < 4; mi++)
#pragma unroll
      for (int ni = 0; ni < 4; ni++) {
        acc[mi][ni]  = __builtin_amdgcn_mfma_f32_16x16x32_f16(ah[mi], bh[ni], acc[mi][ni],  0, 0, 0);
        accx[mi][ni] = __builtin_amdgcn_mfma_f32_16x16x32_f16(ah[mi], bl[ni], accx[mi][ni], 0, 0, 0);
        accx[mi][ni] = __builtin_amdgcn_mfma_f32_16x16x32_f16(al[mi], bh[ni], accx[mi][ni], 0, 0, 0);
      }

    __syncthreads();  // drains vmcnt(0): next buffer staged; cur reads done
    cur ^= 1;
  }

  // Epilogue: per (h,b) abs-argmax over n=32 rows, first-index ties (numpy),
  // then gate RMW on out. C/D frag: col=lane&15 (b), row=(lane>>4)*4+reg (n').
#pragma unroll
  for (int hh = 0; hh < 2; ++hh) {
#pragma unroll
    for (int ni = 0; ni < 4; ++ni) {
      float bestA = -1.f, bestV = 0.f;
      int   bestN = 999;
#pragma unroll
      for (int m2 = 0; m2 < 2; ++m2) {
        const int mi = hh * 2 + m2;
#pragma unroll
        for (int reg = 0; reg < 4; ++reg) {
          const float v = acc[mi][ni][reg] + accx[mi][ni][reg] * 0.00390625f;
          const float a = fabsf(v);
          const int   n = m2 * 16 + g * 4 + reg;   // ascending within thread
          if (a > bestA) { bestA = a; bestV = v; bestN = n; }
        }
      }
#pragma unroll
      for (int m = 16; m <= 32; m <<= 1) {
        const float oa = __shfl_xor(bestA, m, 64);
        const float ov = __shfl_xor(bestV, m, 64);
        const int   on = __shfl_xor(bestN, m, 64);
        if (oa > bestA || (oa == bestA && on < bestN)) {
          bestA = oa; bestV = ov; bestN = on;
        }
      }
      if (g == 0) {
        const int bcol = btile * 128 + wcol0 + ni * 16 + c15;
        const int h    = ntile * 4 + (wv >> 1) * 2 + hh;
        const float gate = 1.f / (1.f + expf(-bestV));
        out[(size_t)bcol * Hdim + h] *= gate;
      }
    }
  }
}

// ---------------------------------------------------------------------------
// Fallback distal kernel (R1, fp32 VALU) if ws is too small.
// ---------------------------------------------------------------------------
__global__ __launch_bounds__(256) void distal_gate_fb(
    const float* __restrict__ din, const float* __restrict__ distal,
    float* __restrict__ out)
{
  __shared__ float Blds[32 * 256];
  __shared__ float Alds[32 * 32];
  const int t  = threadIdx.x;
  const int l  = t & 63;
  const int wv = t >> 6;
  const int ell   = blockIdx.x;
  const int xcd   = ell & 7;
  const int q     = ell >> 3;
  const int htile = xcd * 64 + (q >> 5);
  const int btile = q & 31;
  const int n0 = htile * 256, b0 = btile * 32;

  float acc[8][4];
#pragma unroll
  for (int i = 0; i < 8; i++)
    for (int j = 0; j < 4; j++) acc[i][j] = 0.f;

  const float* brow = distal + (size_t)(n0 + t) * Ddim;
  const int ab = t >> 3, ak = (t & 7) * 4;
  const float* arow = din + (size_t)(b0 + ab) * Ddim + ak;

  for (int kt = 0; kt < Ddim / 32; ++kt) {
    const int d0 = kt * 32;
    float wbuf[32];
#pragma unroll
    for (int f = 0; f < 8; f++) {
      float4 v = *(const float4*)(brow + d0 + f * 4);
      wbuf[f * 4 + 0] = v.x; wbuf[f * 4 + 1] = v.y;
      wbuf[f * 4 + 2] = v.z; wbuf[f * 4 + 3] = v.w;
    }
    float4 av = *(const float4*)(arow + d0);
    __syncthreads();
#pragma unroll
    for (int f = 0; f < 32; f++) Blds[f * 256 + t] = wbuf[f];
    Alds[(ak + 0) * 32 + ab] = av.x;
    Alds[(ak + 1) * 32 + ab] = av.y;
    Alds[(ak + 2) * 32 + ab] = av.z;
    Alds[(ak + 3) * 32 + ab] = av.w;
    __syncthreads();
#pragma unroll
    for (int k = 0; k < 32; k++) {
      float4 bv  = *(const float4*)&Blds[k * 256 + 4 * l];
      float4 alo = *(const float4*)&Alds[k * 32 + 8 * wv];
      float4 ahi = *(const float4*)&Alds[k * 32 + 8 * wv + 4];
      float a0[8] = {alo.x, alo.y, alo.z, alo.w, ahi.x, ahi.y, ahi.z, ahi.w};
#pragma unroll
      for (int i = 0; i < 8; i++) {
        acc[i][0] += a0[i] * bv.x;
        acc[i][1] += a0[i] * bv.y;
        acc[i][2] += a0[i] * bv.z;
        acc[i][3] += a0[i] * bv.w;
      }
    }
  }
  const int i0  = l & 7;
  const int grp = l >> 3;
  float v = 0.f;
#pragma unroll
  for (int bi = 0; bi < 8; bi++) {
    float bav = fabsf(acc[bi][0]);
    float bv_ = acc[bi][0];
    int   bn  = 4 * i0;
#pragma unroll
    for (int j = 1; j < 4; j++) {
      float av2 = fabsf(acc[bi][j]);
      if (av2 > bav) { bav = av2; bv_ = acc[bi][j]; bn = 4 * i0 + j; }
    }
#pragma unroll
    for (int m = 1; m < 8; m <<= 1) {
      float oav = __shfl_xor(bav, m, 64);
      float ov  = __shfl_xor(bv_, m, 64);
      int   on  = __shfl_xor(bn,  m, 64);
      if (oav > bav || (oav == bav && on < bn)) { bav = oav; bv_ = ov; bn = on; }
    }
    if (bi == i0) v = bv_;
  }
  const float gate = 1.f / (1.f + expf(-v));
  const size_t idx = (size_t)(b0 + 8 * wv + i0) * Hdim + (size_t)htile * 8 + grp;
  out[idx] *= gate;
}

// ---------------------------------------------------------------------------
// Kernel 3: per-row top-k mask (unchanged).
// ---------------------------------------------------------------------------
__device__ __forceinline__ unsigned keyf(float f) {
  unsigned u = __float_as_uint(f);
  return (u & 0x80000000u) ? ~u : (u | 0x80000000u);
}

__global__ __launch_bounds__(256) void topk_mask(float* __restrict__ out)
{
  __shared__ float vals[Hdim];
  __shared__ unsigned hist[256];
  __shared__ unsigned sc[4];
  __shared__ unsigned s_prefix, s_kk;
  const int t = threadIdx.x;
  float* row = out + (size_t)blockIdx.x * Hdim;

#pragma unroll
  for (int qq = 0; qq < 4; qq++) {
    float4 v = *(const float4*)(row + qq * 1024 + t * 4);
    *(float4*)&vals[qq * 1024 + t * 4] = v;
  }
  if (t == 0) { s_prefix = 0u; s_kk = Ktop; }
  __syncthreads();

  for (int shift = 24; shift >= 0; shift -= 8) {
    hist[t] = 0u;
    __syncthreads();
    const unsigned prefix = s_prefix;
    const unsigned maskhi = (shift == 24) ? 0u : (0xFFFFFFFFu << (shift + 8));
    for (int c = 0; c < 16; c++) {
      unsigned u = keyf(vals[c * 256 + t]);
      if ((u & maskhi) == prefix)
        atomicAdd(&hist[(u >> shift) & 255u], 1u);
    }
    __syncthreads();
    if (t == 0) {
      unsigned kk = s_kk, cum = 0;
      int bin = 255;
      for (; bin > 0; --bin) {
        unsigned c = hist[bin];
        if (cum + c >= kk) break;
        cum += c;
      }
      s_kk = kk - cum;
      s_prefix = prefix | ((unsigned)bin << shift);
    }
    __syncthreads();
  }
  const unsigned T  = s_prefix;
  const unsigned kk = s_kk;

  const int lane = t & 63, w = t >> 6;
  unsigned running = 0;
  for (int c = 0; c < 16; c++) {
    const int h = c * 256 + t;
    const float v = vals[h];
    const unsigned u = keyf(v);
    const bool tie = (u == T);
    unsigned long long m = __ballot(tie);
    unsigned lpfx = (unsigned)__popcll(m & ((1ull << lane) - 1ull));
    if (lane == 0) sc[w] = (unsigned)__popcll(m);
    __syncthreads();
    unsigned off = 0;
#pragma unroll
    for (int ww = 0; ww < 4; ww++) if (ww < w) off += sc[ww];
    const unsigned rank = running + off + lpfx;
    row[h] = (u > T) ? v : ((tie && rank < kk) ? v : 0.f);
    const unsigned tot = sc[0] + sc[1] + sc[2] + sc[3];
    __syncthreads();
    running += tot;
  }
}

extern "C" void kernel_launch(void* const* d_in, const int* in_sizes, int n_in,
                              void* d_out, int out_size, void* d_ws, size_t ws_size,
                              hipStream_t stream)
{
  (void)in_sizes; (void)n_in; (void)out_size;
  const float* pin  = (const float*)d_in[0];  // (B,P)
  const float* dinp = (const float*)d_in[1];  // (B,D)
  const float* W    = (const float*)d_in[2];  // (H,P)
  const float* bias = (const float*)d_in[3];  // (H,)
  const float* dst  = (const float*)d_in[4];  // (H,N,D)
  float* out = (float*)d_out;                 // (B,H)

  hipLaunchKernelGGL(proximal_gemm, dim3(512), dim3(256), 0, stream, pin, W, bias, out);

  if (ws_size >= WS_NEEDED) {
    char* Aw = (char*)d_ws;                 // 256 MB distal images
    char* Bw = (char*)d_ws + 268435456ull;  // 2 MB din images
    hipLaunchKernelGGL(convert_distal, dim3(32768), dim3(256), 0, stream, dst,  Aw);
    hipLaunchKernelGGL(convert_din,    dim3(256),   dim3(256), 0, stream, dinp, Bw);
    hipLaunchKernelGGL(distal_mfma,    dim3(8192),  dim3(256), 0, stream, Aw, Bw, out);
  } else {
    hipLaunchKernelGGL(distal_gate_fb, dim3(16384), dim3(256), 0, stream, dinp, dst, out);
  }

  hipLaunchKernelGGL(topk_mask, dim3(Bsz), dim3(256), 0, stream, out);
}

// Round 6
// 597.742 us; speedup vs baseline: 5.0190x; 1.1699x over previous
//
#include <hip/hip_runtime.h>
#include <cstdint>
#include <cmath>

#define Bsz  1024
#define Pdim 1024
#define Hdim 4096
#define Ndim 32
#define Ddim 512
#define Ktop 128

typedef _Float16 f16x8 __attribute__((ext_vector_type(8)));
typedef float    f32x4 __attribute__((ext_vector_type(4)));

#define GLDS(gsrc, ldst)                                                        \
  __builtin_amdgcn_global_load_lds(                                             \
      (const __attribute__((address_space(1))) unsigned int*)(gsrc),            \
      (__attribute__((address_space(3))) unsigned int*)(ldst), 16, 0, 0)

// ws layout (time-multiplexed, stream-ordered):
//   phase 1: W images  @0      (16 MB),  pin images @16777216 (4 MB)
//   phase 2: distal images @0  (256 MB), din images @268435456 (2 MB)
// Image per (tile-of-128-rows, K-step-of-32) = 16 KB, FRAGMENT-LINEAR:
//   [hi: frag f=0..7][lo*256: frag f=0..7], each frag 1024 B.
// Element (r,k): frag r>>4, byte = ((k>>3)*16 + (r&15))*16 + (k&7)*2.
// ds_read is wave-uniform base + lane*16 -> zero bank conflicts (R5-verified).
#define WS_NEEDED 270532608ull

// ---------------------------------------------------------------------------
// convert: fp32 (rows x Krow) -> fragment-linear hi/lo images.
// kcbits = log2(Krow/8). One thread = one 16B chunk (8 elems along k).
// ---------------------------------------------------------------------------
__global__ __launch_bounds__(256) void convert_img(
    const float* __restrict__ src, char* __restrict__ dst, int kcbits)
{
  const int gid  = blockIdx.x * 256 + threadIdx.x;
  const int row  = gid >> kcbits;
  const int e    = (gid & ((1 << kcbits) - 1)) * 8;
  const int Krow = 8 << kcbits;
  float4 v0 = *(const float4*)(src + (size_t)row * Krow + e);
  float4 v1 = *(const float4*)(src + (size_t)row * Krow + e + 4);
  const int tile = row >> 7, r = row & 127, ks = e >> 5, k = e & 31;
  char* base = dst + (size_t)(tile * (Krow >> 5) + ks) * 16384;
  const int off = (r >> 4) * 1024 + ((k >> 3) * 16 + (r & 15)) * 16;
  const float f[8] = {v0.x, v0.y, v0.z, v0.w, v1.x, v1.y, v1.z, v1.w};
  f16x8 hi, lo;
#pragma unroll
  for (int j = 0; j < 8; j++) {
    const _Float16 h = (_Float16)f[j];
    hi[j] = h;
    lo[j] = (_Float16)((f[j] - (float)h) * 256.f);
  }
  *(f16x8*)(base + off)        = hi;
  *(f16x8*)(base + 8192 + off) = lo;
}

// ---------------------------------------------------------------------------
// proximal GEMM via fp16 3-term split MFMA (same machinery as distal_mfma).
// C tile 128 (h) x 128 (b), K=1024 in 32 steps. Epilogue: +bias, store.
// Grid 256 = 32 htiles x 8 btiles, htiles pinned per XCD.
// ---------------------------------------------------------------------------
__global__ __launch_bounds__(256, 2) void proximal_mfma(
    const char* __restrict__ Aw, const char* __restrict__ Bw,
    const float* __restrict__ bias, float* __restrict__ out)
{
  __shared__ __align__(16) char lds[2][32768];
  const int t = threadIdx.x, lane = t & 63, wv = t >> 6;
  const int g = lane >> 4, c15 = lane & 15;
  const int wrow0 = (wv >> 1) * 64, wcol0 = (wv & 1) * 64;

  const int blk = blockIdx.x;
  const int xcd = blk & 7, q = blk >> 3;
  const int htile = xcd * 4 + (q >> 3);   // [0,32)
  const int btile = q & 7;                // [0,8)
  const int h0 = htile * 128, b0 = btile * 128;

  f32x4 acc[4][4], accx[4][4];
#pragma unroll
  for (int mi = 0; mi < 4; mi++)
#pragma unroll
    for (int ni = 0; ni < 4; ni++) {
      acc[mi][ni]  = (f32x4){0.f, 0.f, 0.f, 0.f};
      accx[mi][ni] = (f32x4){0.f, 0.f, 0.f, 0.f};
    }

  const char* Abase = Aw + (size_t)(htile * 32) * 16384;
  const char* Bbase = Bw + (size_t)(btile * 32) * 16384;

  auto STAGE = [&](char* bufp, int ks) {
    const char* As = Abase + ks * 16384;
    const char* Bs = Bbase + ks * 16384;
#pragma unroll
    for (int j = 0; j < 4; j++) {
      const int ch = j * 4 + wv;
      GLDS(As + ch * 1024 + lane * 16, bufp + ch * 1024);
      GLDS(Bs + ch * 1024 + lane * 16, bufp + 16384 + ch * 1024);
    }
  };

  STAGE(lds[0], 0);
  __syncthreads();

  int cur = 0;
  for (int ks = 0; ks < 32; ++ks) {
    if (ks < 31) STAGE(lds[cur ^ 1], ks + 1);

    const char* L = lds[cur];
    f16x8 ah[4], al[4];
#pragma unroll
    for (int mi = 0; mi < 4; mi++) {
      const int f = (wv >> 1) * 4 + mi;
      ah[mi] = *(const f16x8*)(L + f * 1024 + lane * 16);
      al[mi] = *(const f16x8*)(L + 8192 + f * 1024 + lane * 16);
    }
    __builtin_amdgcn_s_setprio(1);
#pragma unroll
    for (int ni = 0; ni < 4; ni++) {
      const int f = (wv & 1) * 4 + ni;
      const f16x8 bh = *(const f16x8*)(L + 16384 + f * 1024 + lane * 16);
      const f16x8 bl = *(const f16x8*)(L + 24576 + f * 1024 + lane * 16);
#pragma unroll
      for (int mi = 0; mi < 4; mi++) {
        acc[mi][ni]  = __builtin_amdgcn_mfma_f32_16x16x32_f16(ah[mi], bh, acc[mi][ni],  0, 0, 0);
        accx[mi][ni] = __builtin_amdgcn_mfma_f32_16x16x32_f16(ah[mi], bl, accx[mi][ni], 0, 0, 0);
        accx[mi][ni] = __builtin_amdgcn_mfma_f32_16x16x32_f16(al[mi], bh, accx[mi][ni], 0, 0, 0);
      }
    }
    __builtin_amdgcn_s_setprio(0);
    __syncthreads();
    cur ^= 1;
  }

  // Epilogue: C/D frag col=lane&15 (b), row=(lane>>4)*4+reg (h). +bias, store.
#pragma unroll
  for (int mi = 0; mi < 4; ++mi) {
    const int hb = h0 + wrow0 + mi * 16 + g * 4;
    const float4 bb = *(const float4*)(bias + hb);
#pragma unroll
    for (int ni = 0; ni < 4; ++ni) {
      const int bcol = b0 + wcol0 + ni * 16 + c15;
      float4 o;
      o.x = acc[mi][ni][0] + accx[mi][ni][0] * 0.00390625f + bb.x;
      o.y = acc[mi][ni][1] + accx[mi][ni][1] * 0.00390625f + bb.y;
      o.z = acc[mi][ni][2] + accx[mi][ni][2] * 0.00390625f + bb.z;
      o.w = acc[mi][ni][3] + accx[mi][ni][3] * 0.00390625f + bb.w;
      *(float4*)(out + (size_t)bcol * Hdim + hb) = o;
    }
  }
}

// ---------------------------------------------------------------------------
// distal GEMM via fp16 3-term split MFMA, double-buffered LDS, zero-conflict
// fragment-linear layout; per-ni interleaved reads + setprio around MFMAs.
// Epilogue: abs-argmax over n + sigmoid gate RMW on out.
// ---------------------------------------------------------------------------
__global__ __launch_bounds__(256, 2) void distal_mfma(
    const char* __restrict__ Aw, const char* __restrict__ Bw,
    float* __restrict__ out)
{
  __shared__ __align__(16) char lds[2][32768];
  const int t = threadIdx.x, lane = t & 63, wv = t >> 6;
  const int g = lane >> 4, c15 = lane & 15;
  const int wrow0 = (wv >> 1) * 64, wcol0 = (wv & 1) * 64;

  const int blk = blockIdx.x;
  const int xcd = blk & 7, q = blk >> 3;
  const int ntile = xcd * 128 + (q >> 3);   // [0,1024)
  const int btile = q & 7;                  // [0,8)

  f32x4 acc[4][4], accx[4][4];
#pragma unroll
  for (int mi = 0; mi < 4; mi++)
#pragma unroll
    for (int ni = 0; ni < 4; ni++) {
      acc[mi][ni]  = (f32x4){0.f, 0.f, 0.f, 0.f};
      accx[mi][ni] = (f32x4){0.f, 0.f, 0.f, 0.f};
    }

  const char* Abase = Aw + (size_t)(ntile * 16) * 16384;
  const char* Bbase = Bw + (size_t)(btile * 16) * 16384;

  auto STAGE = [&](char* bufp, int ks) {
    const char* As = Abase + ks * 16384;
    const char* Bs = Bbase + ks * 16384;
#pragma unroll
    for (int j = 0; j < 4; j++) {
      const int ch = j * 4 + wv;
      GLDS(As + ch * 1024 + lane * 16, bufp + ch * 1024);
      GLDS(Bs + ch * 1024 + lane * 16, bufp + 16384 + ch * 1024);
    }
  };

  STAGE(lds[0], 0);
  __syncthreads();

  int cur = 0;
  for (int ks = 0; ks < 16; ++ks) {
    if (ks < 15) STAGE(lds[cur ^ 1], ks + 1);

    const char* L = lds[cur];
    f16x8 ah[4], al[4];
#pragma unroll
    for (int mi = 0; mi < 4; mi++) {
      const int f = (wv >> 1) * 4 + mi;
      ah[mi] = *(const f16x8*)(L + f * 1024 + lane * 16);
      al[mi] = *(const f16x8*)(L + 8192 + f * 1024 + lane * 16);
    }
    __builtin_amdgcn_s_setprio(1);
#pragma unroll
    for (int ni = 0; ni < 4; ni++) {
      const int f = (wv & 1) * 4 + ni;
      const f16x8 bh = *(const f16x8*)(L + 16384 + f * 1024 + lane * 16);
      const f16x8 bl = *(const f16x8*)(L + 24576 + f * 1024 + lane * 16);
#pragma unroll
      for (int mi = 0; mi < 4; mi++) {
        acc[mi][ni]  = __builtin_amdgcn_mfma_f32_16x16x32_f16(ah[mi], bh, acc[mi][ni],  0, 0, 0);
        accx[mi][ni] = __builtin_amdgcn_mfma_f32_16x16x32_f16(ah[mi], bl, accx[mi][ni], 0, 0, 0);
        accx[mi][ni] = __builtin_amdgcn_mfma_f32_16x16x32_f16(al[mi], bh, accx[mi][ni], 0, 0, 0);
      }
    }
    __builtin_amdgcn_s_setprio(0);
    __syncthreads();
    cur ^= 1;
  }

  // Epilogue: per (h,b) abs-argmax over n=32 rows, first-index ties (numpy),
  // then gate RMW on out. C/D frag: col=lane&15 (b), row=(lane>>4)*4+reg (n').
#pragma unroll
  for (int hh = 0; hh < 2; ++hh) {
#pragma unroll
    for (int ni = 0; ni < 4; ++ni) {
      float bestA = -1.f, bestV = 0.f;
      int   bestN = 999;
#pragma unroll
      for (int m2 = 0; m2 < 2; ++m2) {
        const int mi = hh * 2 + m2;
#pragma unroll
        for (int reg = 0; reg < 4; ++reg) {
          const float v = acc[mi][ni][reg] + accx[mi][ni][reg] * 0.00390625f;
          const float a = fabsf(v);
          const int   n = m2 * 16 + g * 4 + reg;   // ascending within thread
          if (a > bestA) { bestA = a; bestV = v; bestN = n; }
        }
      }
#pragma unroll
      for (int m = 16; m <= 32; m <<= 1) {
        const float oa = __shfl_xor(bestA, m, 64);
        const float ov = __shfl_xor(bestV, m, 64);
        const int   on = __shfl_xor(bestN, m, 64);
        if (oa > bestA || (oa == bestA && on < bestN)) {
          bestA = oa; bestV = ov; bestN = on;
        }
      }
      if (g == 0) {
        const int bcol = btile * 128 + wcol0 + ni * 16 + c15;
        const int h    = ntile * 4 + (wv >> 1) * 2 + hh;
        const float gate = 1.f / (1.f + expf(-bestV));
        out[(size_t)bcol * Hdim + h] *= gate;
      }
    }
  }
}

// ---------------------------------------------------------------------------
// Fallback fp32 kernels (only if ws is too small; dead on this harness).
// ---------------------------------------------------------------------------
__global__ __launch_bounds__(256) void proximal_gemm(
    const float* __restrict__ pin, const float* __restrict__ W,
    const float* __restrict__ bias, float* __restrict__ out)
{
  __shared__ float Blds[32 * 256];
  __shared__ float Alds[32 * 32];
  const int t  = threadIdx.x;
  const int l  = t & 63;
  const int wv = t >> 6;
  const int ell   = blockIdx.x;
  const int xcd   = ell & 7;
  const int q     = ell >> 3;
  const int htile = xcd * 2 + (q >> 5);
  const int btile = q & 31;
  const int h0 = htile * 256, b0 = btile * 32;

  float acc[8][4];
#pragma unroll
  for (int i = 0; i < 8; i++)
    for (int j = 0; j < 4; j++) acc[i][j] = 0.f;

  const float* wrow = W + (size_t)(h0 + t) * Pdim;
  const int ab = t >> 3, ak = (t & 7) * 4;
  const float* arow = pin + (size_t)(b0 + ab) * Pdim + ak;

  for (int kt = 0; kt < Pdim / 32; ++kt) {
    const int p0 = kt * 32;
    float wbuf[32];
#pragma unroll
    for (int f = 0; f < 8; f++) {
      float4 v = *(const float4*)(wrow + p0 + f * 4);
      wbuf[f * 4 + 0] = v.x; wbuf[f * 4 + 1] = v.y;
      wbuf[f * 4 + 2] = v.z; wbuf[f * 4 + 3] = v.w;
    }
    float4 av = *(const float4*)(arow + p0);
    __syncthreads();
#pragma unroll
    for (int f = 0; f < 32; f++) Blds[f * 256 + t] = wbuf[f];
    Alds[(ak + 0) * 32 + ab] = av.x;
    Alds[(ak + 1) * 32 + ab] = av.y;
    Alds[(ak + 2) * 32 + ab] = av.z;
    Alds[(ak + 3) * 32 + ab] = av.w;
    __syncthreads();
#pragma unroll
    for (int k = 0; k < 32; k++) {
      float4 bv  = *(const float4*)&Blds[k * 256 + 4 * l];
      float4 alo = *(const float4*)&Alds[k * 32 + 8 * wv];
      float4 ahi = *(const float4*)&Alds[k * 32 + 8 * wv + 4];
      float a0[8] = {alo.x, alo.y, alo.z, alo.w, ahi.x, ahi.y, ahi.z, ahi.w};
#pragma unroll
      for (int i = 0; i < 8; i++) {
        acc[i][0] += a0[i] * bv.x;
        acc[i][1] += a0[i] * bv.y;
        acc[i][2] += a0[i] * bv.z;
        acc[i][3] += a0[i] * bv.w;
      }
    }
  }
  float4 bb = *(const float4*)(bias + h0 + 4 * l);
#pragma unroll
  for (int i = 0; i < 8; i++) {
    float4 o;
    o.x = acc[i][0] + bb.x;
    o.y = acc[i][1] + bb.y;
    o.z = acc[i][2] + bb.z;
    o.w = acc[i][3] + bb.w;
    *(float4*)(out + (size_t)(b0 + 8 * wv + i) * Hdim + h0 + 4 * l) = o;
  }
}

__global__ __launch_bounds__(256) void distal_gate_fb(
    const float* __restrict__ din, const float* __restrict__ distal,
    float* __restrict__ out)
{
  __shared__ float Blds[32 * 256];
  __shared__ float Alds[32 * 32];
  const int t  = threadIdx.x;
  const int l  = t & 63;
  const int wv = t >> 6;
  const int ell   = blockIdx.x;
  const int xcd   = ell & 7;
  const int q     = ell >> 3;
  const int htile = xcd * 64 + (q >> 5);
  const int btile = q & 31;
  const int n0 = htile * 256, b0 = btile * 32;

  float acc[8][4];
#pragma unroll
  for (int i = 0; i < 8; i++)
    for (int j = 0; j < 4; j++) acc[i][j] = 0.f;

  const float* brow = distal + (size_t)(n0 + t) * Ddim;
  const int ab = t >> 3, ak = (t & 7) * 4;
  const float* arow = din + (size_t)(b0 + ab) * Ddim + ak;

  for (int kt = 0; kt < Ddim / 32; ++kt) {
    const int d0 = kt * 32;
    float wbuf[32];
#pragma unroll
    for (int f = 0; f < 8; f++) {
      float4 v = *(const float4*)(brow + d0 + f * 4);
      wbuf[f * 4 + 0] = v.x; wbuf[f * 4 + 1] = v.y;
      wbuf[f * 4 + 2] = v.z; wbuf[f * 4 + 3] = v.w;
    }
    float4 av = *(const float4*)(arow + d0);
    __syncthreads();
#pragma unroll
    for (int f = 0; f < 32; f++) Blds[f * 256 + t] = wbuf[f];
    Alds[(ak + 0) * 32 + ab] = av.x;
    Alds[(ak + 1) * 32 + ab] = av.y;
    Alds[(ak + 2) * 32 + ab] = av.z;
    Alds[(ak + 3) * 32 + ab] = av.w;
    __syncthreads();
#pragma unroll
    for (int k = 0; k < 32; k++) {
      float4 bv  = *(const float4*)&Blds[k * 256 + 4 * l];
      float4 alo = *(const float4*)&Alds[k * 32 + 8 * wv];
      float4 ahi = *(const float4*)&Alds[k * 32 + 8 * wv + 4];
      float a0[8] = {alo.x, alo.y, alo.z, alo.w, ahi.x, ahi.y, ahi.z, ahi.w};
#pragma unroll
      for (int i = 0; i < 8; i++) {
        acc[i][0] += a0[i] * bv.x;
        acc[i][1] += a0[i] * bv.y;
        acc[i][2] += a0[i] * bv.z;
        acc[i][3] += a0[i] * bv.w;
      }
    }
  }
  const int i0  = l & 7;
  const int grp = l >> 3;
  float v = 0.f;
#pragma unroll
  for (int bi = 0; bi < 8; bi++) {
    float bav = fabsf(acc[bi][0]);
    float bv_ = acc[bi][0];
    int   bn  = 4 * i0;
#pragma unroll
    for (int j = 1; j < 4; j++) {
      float av2 = fabsf(acc[bi][j]);
      if (av2 > bav) { bav = av2; bv_ = acc[bi][j]; bn = 4 * i0 + j; }
    }
#pragma unroll
    for (int m = 1; m < 8; m <<= 1) {
      float oav = __shfl_xor(bav, m, 64);
      float ov  = __shfl_xor(bv_, m, 64);
      int   on  = __shfl_xor(bn,  m, 64);
      if (oav > bav || (oav == bav && on < bn)) { bav = oav; bv_ = ov; bn = on; }
    }
    if (bi == i0) v = bv_;
  }
  const float gate = 1.f / (1.f + expf(-v));
  const size_t idx = (size_t)(b0 + 8 * wv + i0) * Hdim + (size_t)htile * 8 + grp;
  out[idx] *= gate;
}

// ---------------------------------------------------------------------------
// per-row top-k mask (unchanged, verified R1-R5).
// ---------------------------------------------------------------------------
__device__ __forceinline__ unsigned keyf(float f) {
  unsigned u = __float_as_uint(f);
  return (u & 0x80000000u) ? ~u : (u | 0x80000000u);
}

__global__ __launch_bounds__(256) void topk_mask(float* __restrict__ out)
{
  __shared__ float vals[Hdim];
  __shared__ unsigned hist[256];
  __shared__ unsigned sc[4];
  __shared__ unsigned s_prefix, s_kk;
  const int t = threadIdx.x;
  float* row = out + (size_t)blockIdx.x * Hdim;

#pragma unroll
  for (int qq = 0; qq < 4; qq++) {
    float4 v = *(const float4*)(row + qq * 1024 + t * 4);
    *(float4*)&vals[qq * 1024 + t * 4] = v;
  }
  if (t == 0) { s_prefix = 0u; s_kk = Ktop; }
  __syncthreads();

  for (int shift = 24; shift >= 0; shift -= 8) {
    hist[t] = 0u;
    __syncthreads();
    const unsigned prefix = s_prefix;
    const unsigned maskhi = (shift == 24) ? 0u : (0xFFFFFFFFu << (shift + 8));
    for (int c = 0; c < 16; c++) {
      unsigned u = keyf(vals[c * 256 + t]);
      if ((u & maskhi) == prefix)
        atomicAdd(&hist[(u >> shift) & 255u], 1u);
    }
    __syncthreads();
    if (t == 0) {
      unsigned kk = s_kk, cum = 0;
      int bin = 255;
      for (; bin > 0; --bin) {
        unsigned c = hist[bin];
        if (cum + c >= kk) break;
        cum += c;
      }
      s_kk = kk - cum;
      s_prefix = prefix | ((unsigned)bin << shift);
    }
    __syncthreads();
  }
  const unsigned T  = s_prefix;
  const unsigned kk = s_kk;

  const int lane = t & 63, w = t >> 6;
  unsigned running = 0;
  for (int c = 0; c < 16; c++) {
    const int h = c * 256 + t;
    const float v = vals[h];
    const unsigned u = keyf(v);
    const bool tie = (u == T);
    unsigned long long m = __ballot(tie);
    unsigned lpfx = (unsigned)__popcll(m & ((1ull << lane) - 1ull));
    if (lane == 0) sc[w] = (unsigned)__popcll(m);
    __syncthreads();
    unsigned off = 0;
#pragma unroll
    for (int ww = 0; ww < 4; ww++) if (ww < w) off += sc[ww];
    const unsigned rank = running + off + lpfx;
    row[h] = (u > T) ? v : ((tie && rank < kk) ? v : 0.f);
    const unsigned tot = sc[0] + sc[1] + sc[2] + sc[3];
    __syncthreads();
    running += tot;
  }
}

extern "C" void kernel_launch(void* const* d_in, const int* in_sizes, int n_in,
                              void* d_out, int out_size, void* d_ws, size_t ws_size,
                              hipStream_t stream)
{
  (void)in_sizes; (void)n_in; (void)out_size;
  const float* pin  = (const float*)d_in[0];  // (B,P)
  const float* dinp = (const float*)d_in[1];  // (B,D)
  const float* W    = (const float*)d_in[2];  // (H,P)
  const float* bias = (const float*)d_in[3];  // (H,)
  const float* dst  = (const float*)d_in[4];  // (H,N,D)
  float* out = (float*)d_out;                 // (B,H)

  if (ws_size >= WS_NEEDED) {
    char* ws = (char*)d_ws;
    // phase 1: proximal (W images @0, pin images @16MB — overwritten later)
    hipLaunchKernelGGL(convert_img,   dim3(2048),  dim3(256), 0, stream, W,   ws,             7);
    hipLaunchKernelGGL(convert_img,   dim3(512),   dim3(256), 0, stream, pin, ws + 16777216,  7);
    hipLaunchKernelGGL(proximal_mfma, dim3(256),   dim3(256), 0, stream, ws, ws + 16777216, bias, out);
    // phase 2: distal (distal images @0 overwrite W/pin; din @256MB)
    hipLaunchKernelGGL(convert_img,   dim3(32768), dim3(256), 0, stream, dst,  ws,             6);
    hipLaunchKernelGGL(convert_img,   dim3(256),   dim3(256), 0, stream, dinp, ws + 268435456, 6);
    hipLaunchKernelGGL(distal_mfma,   dim3(8192),  dim3(256), 0, stream, ws, ws + 268435456, out);
  } else {
    hipLaunchKernelGGL(proximal_gemm, dim3(512),   dim3(256), 0, stream, pin, W, bias, out);
    hipLaunchKernelGGL(distal_gate_fb, dim3(16384), dim3(256), 0, stream, dinp, dst, out);
  }

  hipLaunchKernelGGL(topk_mask, dim3(Bsz), dim3(256), 0, stream, out);
}